// Round 11
// baseline (336.534 us; speedup 1.0000x reference)
//
#include <hip/hip_runtime.h>
#include <hip/hip_bf16.h>

// StreamingTransformerLayer on MI355X (gfx950).
// T=8192, D=512, DFF=2048. All-f32 in/out; internal GEMMs in bf16 MFMA.
// Round 11: r10 (329us) + gemm_bt K-loop re-scheduled with the same
// counted-vmcnt two-barrier pipeline that won attention (-21%): dbuf LDS,
// stage(next); vmcnt(8); s_barrier; compute(cur); s_barrier.

using bf16 = __hip_bfloat16;
typedef __attribute__((ext_vector_type(8))) short short8;  // 8 bf16 = 4 VGPR (MFMA frag)
typedef __attribute__((ext_vector_type(4))) float f32x4;

#define T_DIM 8192

#define AS1C(p) (const __attribute__((address_space(1))) void*)(p)
#define AS3P(p) (__attribute__((address_space(3))) void*)(p)
#define GLL16(src, dst) __builtin_amdgcn_global_load_lds(AS1C(src), AS3P(dst), 16, 0, 0)

static __device__ __forceinline__ short f2bfbits(float f) {
  bf16 b = __float2bfloat16(f);
  short s; __builtin_memcpy(&s, &b, 2); return s;
}
static __device__ __forceinline__ float bfbits2f(short s) {
  unsigned u = ((unsigned)(unsigned short)s) << 16;
  float f; __builtin_memcpy(&f, &u, 4); return f;
}

// ---------------- fused f32 -> bf16 weight convert (one launch) -------------
__global__ void cvt4_kernel(
    const float* __restrict__ a, bf16* __restrict__ oa, int na,
    const float* __restrict__ b, bf16* __restrict__ ob, int nb,
    const float* __restrict__ c, bf16* __restrict__ oc, int nc,
    const float* __restrict__ d, bf16* __restrict__ od, int nd)
{
  int i = blockIdx.x * 256 + threadIdx.x;
  if (i < na) { oa[i] = __float2bfloat16(a[i]); return; }
  i -= na;
  if (i < nb) { ob[i] = __float2bfloat16(b[i]); return; }
  i -= nb;
  if (i < nc) { oc[i] = __float2bfloat16(c[i]); return; }
  i -= nc;
  if (i < nd) od[i] = __float2bfloat16(d[i]);
}

// ---------------- LayerNorm: f32 [T,512] -> bf16 [T,512] ----------------
__global__ __launch_bounds__(256) void ln_kernel(
    const float* __restrict__ x, const float* __restrict__ g,
    const float* __restrict__ bb, bf16* __restrict__ h)
{
  const int row = blockIdx.x * 4 + (threadIdx.x >> 6);
  const int lane = threadIdx.x & 63;
  const float* xr = x + (size_t)row * 512 + lane * 8;
  f32x4 v0 = *(const f32x4*)xr;
  f32x4 v1 = *(const f32x4*)(xr + 4);
  float s = 0.f;
#pragma unroll
  for (int j = 0; j < 4; ++j) s += v0[j] + v1[j];
#pragma unroll
  for (int d = 1; d < 64; d <<= 1) s += __shfl_xor(s, d);
  const float mu = s * (1.f / 512.f);
  float vs = 0.f;
#pragma unroll
  for (int j = 0; j < 4; ++j) { float a = v0[j] - mu, b2 = v1[j] - mu; vs += a * a + b2 * b2; }
#pragma unroll
  for (int d = 1; d < 64; d <<= 1) vs += __shfl_xor(vs, d);
  const float rs = rsqrtf(vs * (1.f / 512.f) + 1e-5f);
  const f32x4 g0 = *(const f32x4*)(g + lane * 8);
  const f32x4 g1v = *(const f32x4*)(g + lane * 8 + 4);
  const f32x4 b0 = *(const f32x4*)(bb + lane * 8);
  const f32x4 b1v = *(const f32x4*)(bb + lane * 8 + 4);
  short8 ov;
#pragma unroll
  for (int j = 0; j < 4; ++j) {
    ov[j]     = f2bfbits((v0[j] - mu) * rs * g0[j] + b0[j]);
    ov[j + 4] = f2bfbits((v1[j] - mu) * rs * g1v[j] + b1v[j]);
  }
  *(short8*)(h + (size_t)row * 512 + lane * 8) = ov;
}

// ---------------- GEMM C = A * B^T (128x128 tile, BK=64, 4 waves) ----------
// Counted-vmcnt two-barrier pipeline (T4): dbuf LDS; per K-step:
// stage(next); vmcnt(8) [tail vmcnt(0)]; s_barrier; compute(cur); s_barrier.
// Race audit: overwrite of a buffer is separated from its readers by the
// trailing barrier of the previous iteration; waits wave-uniform.
enum { MODE_BF16 = 0, MODE_GELU = 1, MODE_RESID = 2 };

static __device__ __forceinline__ float gelu_f(float x) {
  float x3 = x * x * x;
  float t = tanhf(0.7978845608028654f * (x + 0.044715f * x3));
  return 0.5f * x * (1.0f + t);
}

template <int MODE>
__global__ __launch_bounds__(256, 2) void gemm_bt(
    const bf16* __restrict__ A, const bf16* __restrict__ B,
    int M, int N, int K,
    bf16* __restrict__ Cb, float* __restrict__ Cf,
    const float* __restrict__ resid, const float* __restrict__ scale)
{
  __shared__ bf16 sA[2][128 * 64];
  __shared__ bf16 sB[2][128 * 64];
  const int tid = threadIdx.x;
  const int lane = tid & 63, wave = tid >> 6;
  const int bm = blockIdx.x, bn = blockIdx.y;
  const int wm = (wave & 1) * 64, wn = (wave >> 1) * 64;
  const int ln = lane & 15, lg = lane >> 4;
  f32x4 acc[4][4] = {};

  auto stage = [&](int c, int kt) {
#pragma unroll
    for (int r = 0; r < 4; ++r) {
      const int s = r * 256 + tid;
      const int ks = s >> 9, rb = (s >> 6) & 7, l = s & 63;
      const bf16* srcA = A + (size_t)(bm * 128 + rb * 16 + (l & 15)) * K + kt * 64 + ks * 32 + (l >> 4) * 8;
      GLL16(srcA, &sA[c][(size_t)(r * 256 + wave * 64) * 8]);
      const bf16* srcB = B + (size_t)(bn * 128 + rb * 16 + (l & 15)) * K + kt * 64 + ks * 32 + (l >> 4) * 8;
      GLL16(srcB, &sB[c][(size_t)(r * 256 + wave * 64) * 8]);
    }
  };

  const int nkt = K >> 6;
  int cur = 0;
  stage(0, 0);   // FIFO: [T0]
  for (int kt = 0; kt < nkt; ++kt) {
    if (kt + 1 < nkt) {
      stage(cur ^ 1, kt + 1);   // FIFO: [Tk Tk+1]
      asm volatile("s_waitcnt vmcnt(8)" ::: "memory");   // Tk landed, Tk+1 in flight
    } else {
      asm volatile("s_waitcnt vmcnt(0)" ::: "memory");   // tail drain
    }
    __builtin_amdgcn_s_barrier();
    __builtin_amdgcn_sched_barrier(0);
#pragma unroll
    for (int ks = 0; ks < 2; ++ks) {
      short8 af[4], bfr[4];
#pragma unroll
      for (int mi = 0; mi < 4; ++mi)
        af[mi] = *(const short8*)(&sA[cur][(size_t)(ks * 512 + ((wm >> 4) + mi) * 64 + lane) * 8]);
#pragma unroll
      for (int ni = 0; ni < 4; ++ni)
        bfr[ni] = *(const short8*)(&sB[cur][(size_t)(ks * 512 + ((wn >> 4) + ni) * 64 + lane) * 8]);
      __builtin_amdgcn_s_setprio(1);
#pragma unroll
      for (int mi = 0; mi < 4; ++mi)
#pragma unroll
        for (int ni = 0; ni < 4; ++ni)
          acc[mi][ni] = __builtin_amdgcn_mfma_f32_16x16x32_bf16(af[mi], bfr[ni], acc[mi][ni], 0, 0, 0);
      __builtin_amdgcn_s_setprio(0);
    }
    __builtin_amdgcn_s_barrier();   // all reads of cur done before next overwrite
    __builtin_amdgcn_sched_barrier(0);
    cur ^= 1;
  }
#pragma unroll
  for (int mi = 0; mi < 4; ++mi) {
#pragma unroll
    for (int ni = 0; ni < 4; ++ni) {
#pragma unroll
      for (int r = 0; r < 4; ++r) {
        const int row = bm * 128 + wm + mi * 16 + lg * 4 + r;
        const int col = bn * 128 + wn + ni * 16 + ln;
        const size_t idx = (size_t)row * N + col;
        float v = acc[mi][ni][r];
        if constexpr (MODE == MODE_GELU) { Cb[idx] = __float2bfloat16(gelu_f(v)); }
        else if constexpr (MODE == MODE_RESID) { Cf[idx] = resid[idx] + scale[col] * v; }
        else { Cb[idx] = __float2bfloat16(v); }
      }
    }
  }
}

// ---------------- V transpose: proj[:,1024:1536] -> vT [512][T] ----------------
__global__ __launch_bounds__(256) void transpose_v(const bf16* __restrict__ proj, bf16* __restrict__ vT) {
  __shared__ bf16 tile[64][66];
  const int t0 = blockIdx.x * 64, d0 = blockIdx.y * 64;
  const int tid = threadIdx.x;
#pragma unroll
  for (int i = 0; i < 16; ++i) {
    const int lin = i * 256 + tid;
    const int r = lin >> 6, c = lin & 63;
    tile[r][c] = proj[(size_t)(t0 + r) * 1536 + 1024 + d0 + c];
  }
  __syncthreads();
#pragma unroll
  for (int i = 0; i < 16; ++i) {
    const int lin = i * 256 + tid;
    const int dy = lin >> 6, tx = lin & 63;
    vT[(size_t)(d0 + dy) * T_DIM + t0 + tx] = tile[tx][dy];
  }
}

// ---------------- causal flash attention (8 waves, 128 rows, T4 schedule) ---
// (unchanged from round 10 -- verified at 154us)
__global__ __launch_bounds__(512, 2) void attn_kernel(
    const bf16* __restrict__ proj, const bf16* __restrict__ vT,
    bf16* __restrict__ Op, float* __restrict__ mlp)
{
  __shared__ bf16 sQ[2][32 * 512];  // slot(ks,jb,l): q row jb*16+(l&15), d ks*32+(l>>4)*8
  __shared__ bf16 sV[2][32 * 512];  // slot(nb,l):   vT row nb*16+(l&15), j (l>>4)*8
  __shared__ bf16 sP[8][16 * 40];   // per-wave P bounce, padded stride 40

  const int tid = threadIdx.x, lane = tid & 63, wave = tid >> 6;
  const int ln = lane & 15, lg = lane >> 4;
  const int b = 511 - blockIdx.x;   // biggest blocks first
  const int it = b >> 3;            // row-tile [0,64)
  const int ch = b & 7;             // chunk [0,8)
  const int nj = 4 * it + 4;        // j-tiles needed by this row-tile
  const int jlo = ch * nj / 8;
  const int jhi = (ch + 1) * nj / 8;
  const int wrow = it * 128 + wave * 16;

  // K rows for this wave in registers (A operand); k = proj cols 512..1023
  short8 kf[16];
#pragma unroll
  for (int ks = 0; ks < 16; ++ks)
    kf[ks] = *(const short8*)(proj + (size_t)(wrow + ln) * 1536 + 512 + ks * 32 + lg * 8);

  f32x4 oa[32] = {};
  float m_r[4] = {-__builtin_inff(), -__builtin_inff(), -__builtin_inff(), -__builtin_inff()};
  float l_r[4] = {0.f, 0.f, 0.f, 0.f};

  // stage halves: 4 GLL16 each (2048 slots of 8 elems over 512 threads)
  auto stageQ = [&](int c, int jt) {
    const int j0 = jt * 32;
#pragma unroll
    for (int r = 0; r < 4; ++r) {
      const int s = r * 512 + tid;
      const int l = s & 63;
      const int ks = s >> 7, jb = (s >> 6) & 1;
      const bf16* srcQ = proj + (size_t)(j0 + jb * 16 + (l & 15)) * 1536 + ks * 32 + (l >> 4) * 8;
      GLL16(srcQ, &sQ[c][(size_t)(r * 512 + wave * 64) * 8]);
    }
  };
  auto stageV = [&](int c, int jt) {
    const int j0 = jt * 32;
#pragma unroll
    for (int r = 0; r < 4; ++r) {
      const int s = r * 512 + tid;
      const int l = s & 63;
      const int nb = s >> 6;
      const bf16* srcV = vT + (size_t)(nb * 16 + (l & 15)) * T_DIM + j0 + (l >> 4) * 8;
      GLL16(srcV, &sV[c][(size_t)(r * 512 + wave * 64) * 8]);
    }
  };

  if (jlo < jhi) {
    int cur = 0;
    stageQ(0, jlo);   // FIFO: [Q0]
    stageV(0, jlo);   // FIFO: [Q0 V0]
    for (int jt = jlo; jt < jhi; ++jt) {
      const int j0 = jt * 32;
      const bool more = (jt + 1 < jhi);
      if (more) stageQ(cur ^ 1, jt + 1);   // FIFO: [Qk Vk Qk+1]
      // wait Q(jt) landed (keep Vk + Qk+1 = 8 in flight), then rendezvous
      if (more) { asm volatile("s_waitcnt vmcnt(8)" ::: "memory"); }
      else      { asm volatile("s_waitcnt vmcnt(4)" ::: "memory"); }
      __builtin_amdgcn_s_barrier();
      __builtin_amdgcn_sched_barrier(0);
      if (j0 <= wrow + 15) {   // wave-uniform causal skip (compute only)
        // ---- QK^T: S[16 i][32 j] as 2 frags ----
        f32x4 sfr[2] = {};
        __builtin_amdgcn_s_setprio(1);
#pragma unroll
        for (int ks = 0; ks < 16; ++ks) {
          short8 q0 = *(const short8*)(&sQ[cur][(size_t)(ks * 128 + lane) * 8]);
          short8 q1 = *(const short8*)(&sQ[cur][(size_t)(ks * 128 + 64 + lane) * 8]);
          sfr[0] = __builtin_amdgcn_mfma_f32_16x16x32_bf16(kf[ks], q0, sfr[0], 0, 0, 0);
          sfr[1] = __builtin_amdgcn_mfma_f32_16x16x32_bf16(kf[ks], q1, sfr[1], 0, 0, 0);
        }
        __builtin_amdgcn_s_setprio(0);
        if (j0 + 31 > wrow) {  // causal mask on diagonal tiles
#pragma unroll
          for (int jb = 0; jb < 2; ++jb)
#pragma unroll
            for (int r = 0; r < 4; ++r) {
              const int i = wrow + lg * 4 + r, j = j0 + jb * 16 + ln;
              if (j > i) sfr[jb][r] = -__builtin_inff();
            }
        }
        // ---- exact online softmax (round-1 math) ----
        float mx[4], sc[4], mm[4];
#pragma unroll
        for (int r = 0; r < 4; ++r) mx[r] = fmaxf(sfr[0][r], sfr[1][r]);
#pragma unroll
        for (int d = 1; d < 16; d <<= 1)
#pragma unroll
          for (int r = 0; r < 4; ++r) mx[r] = fmaxf(mx[r], __shfl_xor(mx[r], d));
#pragma unroll
        for (int r = 0; r < 4; ++r) {
          mm[r] = fmaxf(fmaxf(m_r[r], mx[r]), -1e30f);  // clamp: no NaN from inf-inf
          sc[r] = __expf(m_r[r] - mm[r]);
          m_r[r] = mm[r];
          l_r[r] *= sc[r];
        }
        float ts[4] = {0.f, 0.f, 0.f, 0.f};
#pragma unroll
        for (int jb = 0; jb < 2; ++jb)
#pragma unroll
          for (int r = 0; r < 4; ++r) {
            float p = __expf(sfr[jb][r] - mm[r]);
            sfr[jb][r] = p;
            ts[r] += p;
          }
#pragma unroll
        for (int d = 1; d < 16; d <<= 1)
#pragma unroll
          for (int r = 0; r < 4; ++r) ts[r] += __shfl_xor(ts[r], d);
#pragma unroll
        for (int r = 0; r < 4; ++r) l_r[r] += ts[r];
        // ---- P -> bf16 A-frag via per-wave LDS bounce ----
#pragma unroll
        for (int jb = 0; jb < 2; ++jb)
#pragma unroll
          for (int r = 0; r < 4; ++r)
            sP[wave][(lg * 4 + r) * 40 + jb * 16 + ln] = __float2bfloat16(sfr[jb][r]);
        // rescale O (overlaps LDS ops)
#pragma unroll
        for (int nb = 0; nb < 32; ++nb)
#pragma unroll
          for (int r = 0; r < 4; ++r) oa[nb][r] *= sc[r];
      }
      if (more) stageV(cur ^ 1, jt + 1);   // FIFO: [Vk Qk+1 Vk+1]
      // wait V(jt) landed (keep Qk+1 + Vk+1 = 8 in flight), then rendezvous
      if (more) { asm volatile("s_waitcnt vmcnt(8)" ::: "memory"); }
      else      { asm volatile("s_waitcnt vmcnt(0)" ::: "memory"); }
      __builtin_amdgcn_s_barrier();
      __builtin_amdgcn_sched_barrier(0);
      if (j0 <= wrow + 15) {
        const short8 pa = *(const short8*)(&sP[wave][0] + ln * 40 + lg * 8);
        // ---- PV: O[16][512] += P[16][32] * V[32][512], depth-4 rotation ----
        __builtin_amdgcn_s_setprio(1);
#define LDV(nb) (*(const short8*)(&sV[cur][(size_t)((nb) * 64 + lane) * 8]))
        short8 vf0 = LDV(0), vf1 = LDV(1), vf2 = LDV(2), vf3 = LDV(3);
#pragma unroll
        for (int nb = 0; nb < 28; nb += 4) {
          const short8 w0 = vf0, w1 = vf1, w2 = vf2, w3 = vf3;
          vf0 = LDV(nb + 4); vf1 = LDV(nb + 5); vf2 = LDV(nb + 6); vf3 = LDV(nb + 7);
          oa[nb]     = __builtin_amdgcn_mfma_f32_16x16x32_bf16(pa, w0, oa[nb],     0, 0, 0);
          oa[nb + 1] = __builtin_amdgcn_mfma_f32_16x16x32_bf16(pa, w1, oa[nb + 1], 0, 0, 0);
          oa[nb + 2] = __builtin_amdgcn_mfma_f32_16x16x32_bf16(pa, w2, oa[nb + 2], 0, 0, 0);
          oa[nb + 3] = __builtin_amdgcn_mfma_f32_16x16x32_bf16(pa, w3, oa[nb + 3], 0, 0, 0);
        }
        oa[28] = __builtin_amdgcn_mfma_f32_16x16x32_bf16(pa, vf0, oa[28], 0, 0, 0);
        oa[29] = __builtin_amdgcn_mfma_f32_16x16x32_bf16(pa, vf1, oa[29], 0, 0, 0);
        oa[30] = __builtin_amdgcn_mfma_f32_16x16x32_bf16(pa, vf2, oa[30], 0, 0, 0);
        oa[31] = __builtin_amdgcn_mfma_f32_16x16x32_bf16(pa, vf3, oa[31], 0, 0, 0);
#undef LDV
        __builtin_amdgcn_s_setprio(0);
      }
      cur ^= 1;
    }
  }
  // ---- write partials (bf16, per-element; verified epilogue) ----
#pragma unroll
  for (int nb = 0; nb < 32; ++nb)
#pragma unroll
    for (int r = 0; r < 4; ++r)
      Op[((size_t)ch * T_DIM + wrow + lg * 4 + r) * 512 + nb * 16 + ln] = __float2bfloat16(oa[nb][r]);
  if (ln == 0) {
#pragma unroll
    for (int r = 0; r < 4; ++r) {
      mlp[((size_t)ch * T_DIM + wrow + lg * 4 + r) * 2 + 0] = m_r[r];
      mlp[((size_t)ch * T_DIM + wrow + lg * 4 + r) * 2 + 1] = l_r[r];
    }
  }
}

// ---------------- merge attention partials -> o bf16 [T,512] ----------------
__global__ __launch_bounds__(256) void combine_kernel(
    const bf16* __restrict__ Op, const float* __restrict__ mlp, bf16* __restrict__ o)
{
  const int row = blockIdx.x * 4 + (threadIdx.x >> 6);
  const int lane = threadIdx.x & 63;
  const int k = 8;  // uniform 8 chunks per row-tile
  float m = -__builtin_inff();
  for (int c = 0; c < k; ++c) m = fmaxf(m, mlp[((size_t)c * T_DIM + row) * 2]);
  float l = 0.f;
  for (int c = 0; c < k; ++c) {
    const float mc = mlp[((size_t)c * T_DIM + row) * 2];
    const float lc = mlp[((size_t)c * T_DIM + row) * 2 + 1];
    l += __expf(mc - m) * lc;
  }
  const float inv = 1.0f / l;
  f32x4 a0 = {}, a1 = {};
  for (int c = 0; c < k; ++c) {
    const float w = __expf(mlp[((size_t)c * T_DIM + row) * 2] - m);
    const short8 u = *(const short8*)(Op + ((size_t)c * T_DIM + row) * 512 + lane * 8);
#pragma unroll
    for (int j = 0; j < 4; ++j) {
      a0[j] += w * bfbits2f(u[j]);
      a1[j] += w * bfbits2f(u[j + 4]);
    }
  }
  short8 ov;
#pragma unroll
  for (int j = 0; j < 4; ++j) {
    ov[j]     = f2bfbits(a0[j] * inv);
    ov[j + 4] = f2bfbits(a1[j] * inv);
  }
  *(short8*)(o + (size_t)row * 512 + lane * 8) = ov;
}

// ---------------- launch ----------------
extern "C" void kernel_launch(void* const* d_in, const int* in_sizes, int n_in,
                              void* d_out, int out_size, void* d_ws, size_t ws_size,
                              hipStream_t stream) {
  (void)in_sizes; (void)n_in; (void)out_size; (void)ws_size;
  const float* x    = (const float*)d_in[0];
  const float* Win  = (const float*)d_in[1];
  const float* Wout = (const float*)d_in[2];
  const float* W1   = (const float*)d_in[3];
  const float* W2   = (const float*)d_in[4];
  const float* g1   = (const float*)d_in[5];
  const float* b1   = (const float*)d_in[6];
  const float* g2   = (const float*)d_in[7];
  const float* b2   = (const float*)d_in[8];
  const float* ls1  = (const float*)d_in[9];
  const float* ls2  = (const float*)d_in[10];
  float* out = (float*)d_out;

  char* w = (char*)d_ws;
  size_t off = 0;
  auto alloc = [&](size_t bytes) -> char* {
    char* p = w + off; off += (bytes + 255) & ~(size_t)255; return p;
  };
  bf16* wWin  = (bf16*)alloc((size_t)1536 * 512 * 2);
  bf16* wWout = (bf16*)alloc((size_t)512 * 512 * 2);
  bf16* wW1   = (bf16*)alloc((size_t)2048 * 512 * 2);
  bf16* wW2   = (bf16*)alloc((size_t)512 * 2048 * 2);
  bf16* h     = (bf16*)alloc((size_t)T_DIM * 512 * 2);    // LN1 out; reused for LN2 out
  bf16* proj  = (bf16*)alloc((size_t)T_DIM * 1536 * 2);   // q|k|v
  bf16* vTb   = (bf16*)alloc((size_t)512 * T_DIM * 2);
  bf16* o     = (bf16*)alloc((size_t)T_DIM * 512 * 2);
  float* x1   = (float*)alloc((size_t)T_DIM * 512 * 4);
  bf16* Op    = (bf16*)alloc((size_t)8 * T_DIM * 512 * 2); // 67MB bf16 partials
  float* mlp  = (float*)alloc((size_t)8 * T_DIM * 2 * 4);
  bf16* f1 = proj;  // ffn1 out aliases proj||vT (dead after attention)

  cvt4_kernel<<<(1536 * 512 + 512 * 512 + 2048 * 512 + 512 * 2048 + 255) / 256, 256, 0, stream>>>(
      Win, wWin, 1536 * 512, Wout, wWout, 512 * 512,
      W1, wW1, 2048 * 512, W2, wW2, 512 * 2048);

  ln_kernel<<<T_DIM / 4, 256, 0, stream>>>(x, g1, b1, h);
  gemm_bt<MODE_BF16><<<dim3(64, 12), 256, 0, stream>>>(h, wWin, 8192, 1536, 512, proj, nullptr, nullptr, nullptr);
  transpose_v<<<dim3(T_DIM / 64, 8), 256, 0, stream>>>(proj, vTb);
  attn_kernel<<<512, 512, 0, stream>>>(proj, vTb, Op, mlp);
  combine_kernel<<<T_DIM / 4, 256, 0, stream>>>(Op, mlp, o);
  gemm_bt<MODE_RESID><<<dim3(64, 4), 256, 0, stream>>>(o, wWout, 8192, 512, 512, nullptr, x1, x, ls1);
  ln_kernel<<<T_DIM / 4, 256, 0, stream>>>(x1, g2, b2, h);
  gemm_bt<MODE_GELU><<<dim3(64, 16), 256, 0, stream>>>(h, wW1, 8192, 2048, 512, f1, nullptr, nullptr, nullptr);
  gemm_bt<MODE_RESID><<<dim3(64, 4), 256, 0, stream>>>(f1, wW2, 8192, 512, 2048, nullptr, out, x1, ls2);
}

// Round 12
// 320.278 us; speedup vs baseline: 1.0508x; 1.0508x over previous
//
#include <hip/hip_runtime.h>
#include <hip/hip_bf16.h>

// StreamingTransformerLayer on MI355X (gfx950).
// T=8192, D=512, DFF=2048. All-f32 in/out; internal GEMMs in bf16 MFMA.
// Round 12: r10 base (329us) + (1) gemm_bt reverted to single-buffer schedule
// with XCD-aware bijective block swizzle (bm-major per XCD -> A-panel L2
// residency), (2) attention defer-max (T13, wave-vote, THR=8), (3) cvt x4
// vectorized. Attention T4 schedule unchanged (verified 154us).

using bf16 = __hip_bfloat16;
typedef __attribute__((ext_vector_type(8))) short short8;   // 8 bf16 = 4 VGPR (MFMA frag)
typedef __attribute__((ext_vector_type(4))) short short4v;  // 4 bf16 = 8B
typedef __attribute__((ext_vector_type(4))) float f32x4;

#define T_DIM 8192

#define AS1C(p) (const __attribute__((address_space(1))) void*)(p)
#define AS3P(p) (__attribute__((address_space(3))) void*)(p)
#define GLL16(src, dst) __builtin_amdgcn_global_load_lds(AS1C(src), AS3P(dst), 16, 0, 0)

static __device__ __forceinline__ short f2bfbits(float f) {
  bf16 b = __float2bfloat16(f);
  short s; __builtin_memcpy(&s, &b, 2); return s;
}
static __device__ __forceinline__ float bfbits2f(short s) {
  unsigned u = ((unsigned)(unsigned short)s) << 16;
  float f; __builtin_memcpy(&f, &u, 4); return f;
}

// ---------------- fused f32 -> bf16 weight convert (vectorized x4) ----------
__global__ void cvt4_kernel(
    const float* __restrict__ a, bf16* __restrict__ oa, int na,
    const float* __restrict__ b, bf16* __restrict__ ob, int nb,
    const float* __restrict__ c, bf16* __restrict__ oc, int nc,
    const float* __restrict__ d, bf16* __restrict__ od, int nd)
{
  int i = blockIdx.x * 256 + threadIdx.x;   // index in groups of 4 floats
  const float* src; bf16* dst;
  if (i < na / 4) { src = a; dst = oa; }
  else { i -= na / 4;
    if (i < nb / 4) { src = b; dst = ob; }
    else { i -= nb / 4;
      if (i < nc / 4) { src = c; dst = oc; }
      else { i -= nc / 4;
        if (i >= nd / 4) return;
        src = d; dst = od; } } }
  const f32x4 v = ((const f32x4*)src)[i];
  short4v o;
#pragma unroll
  for (int j = 0; j < 4; ++j) o[j] = f2bfbits(v[j]);
  ((short4v*)dst)[i] = o;
}

// ---------------- LayerNorm: f32 [T,512] -> bf16 [T,512] ----------------
__global__ __launch_bounds__(256) void ln_kernel(
    const float* __restrict__ x, const float* __restrict__ g,
    const float* __restrict__ bb, bf16* __restrict__ h)
{
  const int row = blockIdx.x * 4 + (threadIdx.x >> 6);
  const int lane = threadIdx.x & 63;
  const float* xr = x + (size_t)row * 512 + lane * 8;
  f32x4 v0 = *(const f32x4*)xr;
  f32x4 v1 = *(const f32x4*)(xr + 4);
  float s = 0.f;
#pragma unroll
  for (int j = 0; j < 4; ++j) s += v0[j] + v1[j];
#pragma unroll
  for (int d = 1; d < 64; d <<= 1) s += __shfl_xor(s, d);
  const float mu = s * (1.f / 512.f);
  float vs = 0.f;
#pragma unroll
  for (int j = 0; j < 4; ++j) { float a = v0[j] - mu, b2 = v1[j] - mu; vs += a * a + b2 * b2; }
#pragma unroll
  for (int d = 1; d < 64; d <<= 1) vs += __shfl_xor(vs, d);
  const float rs = rsqrtf(vs * (1.f / 512.f) + 1e-5f);
  const f32x4 g0 = *(const f32x4*)(g + lane * 8);
  const f32x4 g1v = *(const f32x4*)(g + lane * 8 + 4);
  const f32x4 b0 = *(const f32x4*)(bb + lane * 8);
  const f32x4 b1v = *(const f32x4*)(bb + lane * 8 + 4);
  short8 ov;
#pragma unroll
  for (int j = 0; j < 4; ++j) {
    ov[j]     = f2bfbits((v0[j] - mu) * rs * g0[j] + b0[j]);
    ov[j + 4] = f2bfbits((v1[j] - mu) * rs * g1v[j] + b1v[j]);
  }
  *(short8*)(h + (size_t)row * 512 + lane * 8) = ov;
}

// ---------------- GEMM C = A * B^T (128x128 tile, BK=64, 4 waves) ----------
// r10 schedule (single-buffer, __syncthreads) + XCD-aware bijective swizzle:
// lin -> swz = (lin&7)*(nwg/8) + (lin>>3); bm-major decode so each XCD gets
// ~8 contiguous A-panels (1MB) + the B-panel set -> per-XCD-L2 resident.
enum { MODE_BF16 = 0, MODE_GELU = 1, MODE_RESID = 2 };

static __device__ __forceinline__ float gelu_f(float x) {
  float x3 = x * x * x;
  float t = tanhf(0.7978845608028654f * (x + 0.044715f * x3));
  return 0.5f * x * (1.0f + t);
}

template <int MODE>
__global__ __launch_bounds__(256, 2) void gemm_bt(
    const bf16* __restrict__ A, const bf16* __restrict__ B,
    int M, int N, int K,
    bf16* __restrict__ Cb, float* __restrict__ Cf,
    const float* __restrict__ resid, const float* __restrict__ scale)
{
  __shared__ bf16 sA[128 * 64];
  __shared__ bf16 sB[128 * 64];
  const int tid = threadIdx.x;
  const int lane = tid & 63, wave = tid >> 6;
  // XCD-aware bijective swizzle (nwg % 8 == 0 for all our grids)
  const int NB = gridDim.y;
  const int nwg = gridDim.x * NB;
  const int lin = blockIdx.y * gridDim.x + blockIdx.x;
  const int q8 = nwg >> 3;
  const int swz = (lin & 7) * q8 + (lin >> 3);
  const int bm = swz / NB, bn = swz % NB;
  const int wm = (wave & 1) * 64, wn = (wave >> 1) * 64;
  const int ln = lane & 15, lg = lane >> 4;
  f32x4 acc[4][4] = {};

  const int nkt = K >> 6;
  for (int kt = 0; kt < nkt; ++kt) {
    __syncthreads();
#pragma unroll
    for (int r = 0; r < 4; ++r) {
      const int s = r * 256 + tid;
      const int ks = s >> 9, rb = (s >> 6) & 7, l = s & 63;
      const bf16* srcA = A + (size_t)(bm * 128 + rb * 16 + (l & 15)) * K + kt * 64 + ks * 32 + (l >> 4) * 8;
      GLL16(srcA, sA + (size_t)(r * 256 + wave * 64) * 8);
      const bf16* srcB = B + (size_t)(bn * 128 + rb * 16 + (l & 15)) * K + kt * 64 + ks * 32 + (l >> 4) * 8;
      GLL16(srcB, sB + (size_t)(r * 256 + wave * 64) * 8);
    }
    __syncthreads();
#pragma unroll
    for (int ks = 0; ks < 2; ++ks) {
      short8 af[4], bfr[4];
#pragma unroll
      for (int mi = 0; mi < 4; ++mi)
        af[mi] = *(const short8*)(sA + (size_t)(ks * 512 + ((wm >> 4) + mi) * 64 + lane) * 8);
#pragma unroll
      for (int ni = 0; ni < 4; ++ni)
        bfr[ni] = *(const short8*)(sB + (size_t)(ks * 512 + ((wn >> 4) + ni) * 64 + lane) * 8);
#pragma unroll
      for (int mi = 0; mi < 4; ++mi)
#pragma unroll
        for (int ni = 0; ni < 4; ++ni)
          acc[mi][ni] = __builtin_amdgcn_mfma_f32_16x16x32_bf16(af[mi], bfr[ni], acc[mi][ni], 0, 0, 0);
    }
  }
#pragma unroll
  for (int mi = 0; mi < 4; ++mi) {
#pragma unroll
    for (int ni = 0; ni < 4; ++ni) {
#pragma unroll
      for (int r = 0; r < 4; ++r) {
        const int row = bm * 128 + wm + mi * 16 + lg * 4 + r;
        const int col = bn * 128 + wn + ni * 16 + ln;
        const size_t idx = (size_t)row * N + col;
        float v = acc[mi][ni][r];
        if constexpr (MODE == MODE_GELU) { Cb[idx] = __float2bfloat16(gelu_f(v)); }
        else if constexpr (MODE == MODE_RESID) { Cf[idx] = resid[idx] + scale[col] * v; }
        else { Cb[idx] = __float2bfloat16(v); }
      }
    }
  }
}

// ---------------- V transpose: proj[:,1024:1536] -> vT [512][T] ----------------
__global__ __launch_bounds__(256) void transpose_v(const bf16* __restrict__ proj, bf16* __restrict__ vT) {
  __shared__ bf16 tile[64][66];
  const int t0 = blockIdx.x * 64, d0 = blockIdx.y * 64;
  const int tid = threadIdx.x;
#pragma unroll
  for (int i = 0; i < 16; ++i) {
    const int lin = i * 256 + tid;
    const int r = lin >> 6, c = lin & 63;
    tile[r][c] = proj[(size_t)(t0 + r) * 1536 + 1024 + d0 + c];
  }
  __syncthreads();
#pragma unroll
  for (int i = 0; i < 16; ++i) {
    const int lin = i * 256 + tid;
    const int dy = lin >> 6, tx = lin & 63;
    vT[(size_t)(d0 + dy) * T_DIM + t0 + tx] = tile[tx][dy];
  }
}

// ---------------- causal flash attention (8 waves, 128 rows, T4 + T13) ------
// r10 structure + schedule (verified 154us) with defer-max: skip the
// O-rescale/m-update when the whole wave's per-tile max grew by <= 8
// (P then bounded by e^8 -- safe in f32/bf16). NaN audit: first processed
// tile always votes rescale (m=-inf); fully-masked rows give p=0 via
// exp(-inf - finite) or exp(-inf - (-1e30)) = 0 on every path.
__global__ __launch_bounds__(512, 2) void attn_kernel(
    const bf16* __restrict__ proj, const bf16* __restrict__ vT,
    bf16* __restrict__ Op, float* __restrict__ mlp)
{
  __shared__ bf16 sQ[2][32 * 512];  // slot(ks,jb,l): q row jb*16+(l&15), d ks*32+(l>>4)*8
  __shared__ bf16 sV[2][32 * 512];  // slot(nb,l):   vT row nb*16+(l&15), j (l>>4)*8
  __shared__ bf16 sP[8][16 * 40];   // per-wave P bounce, padded stride 40

  const int tid = threadIdx.x, lane = tid & 63, wave = tid >> 6;
  const int ln = lane & 15, lg = lane >> 4;
  const int b = 511 - blockIdx.x;   // biggest blocks first
  const int it = b >> 3;            // row-tile [0,64)
  const int ch = b & 7;             // chunk [0,8)
  const int nj = 4 * it + 4;        // j-tiles needed by this row-tile
  const int jlo = ch * nj / 8;
  const int jhi = (ch + 1) * nj / 8;
  const int wrow = it * 128 + wave * 16;

  // K rows for this wave in registers (A operand); k = proj cols 512..1023
  short8 kf[16];
#pragma unroll
  for (int ks = 0; ks < 16; ++ks)
    kf[ks] = *(const short8*)(proj + (size_t)(wrow + ln) * 1536 + 512 + ks * 32 + lg * 8);

  f32x4 oa[32] = {};
  float m_r[4] = {-__builtin_inff(), -__builtin_inff(), -__builtin_inff(), -__builtin_inff()};
  float l_r[4] = {0.f, 0.f, 0.f, 0.f};

  // stage halves: 4 GLL16 each (2048 slots of 8 elems over 512 threads)
  auto stageQ = [&](int c, int jt) {
    const int j0 = jt * 32;
#pragma unroll
    for (int r = 0; r < 4; ++r) {
      const int s = r * 512 + tid;
      const int l = s & 63;
      const int ks = s >> 7, jb = (s >> 6) & 1;
      const bf16* srcQ = proj + (size_t)(j0 + jb * 16 + (l & 15)) * 1536 + ks * 32 + (l >> 4) * 8;
      GLL16(srcQ, &sQ[c][(size_t)(r * 512 + wave * 64) * 8]);
    }
  };
  auto stageV = [&](int c, int jt) {
    const int j0 = jt * 32;
#pragma unroll
    for (int r = 0; r < 4; ++r) {
      const int s = r * 512 + tid;
      const int l = s & 63;
      const int nb = s >> 6;
      const bf16* srcV = vT + (size_t)(nb * 16 + (l & 15)) * T_DIM + j0 + (l >> 4) * 8;
      GLL16(srcV, &sV[c][(size_t)(r * 512 + wave * 64) * 8]);
    }
  };

  if (jlo < jhi) {
    int cur = 0;
    stageQ(0, jlo);   // FIFO: [Q0]
    stageV(0, jlo);   // FIFO: [Q0 V0]
    for (int jt = jlo; jt < jhi; ++jt) {
      const int j0 = jt * 32;
      const bool more = (jt + 1 < jhi);
      if (more) stageQ(cur ^ 1, jt + 1);   // FIFO: [Qk Vk Qk+1]
      // wait Q(jt) landed (keep Vk + Qk+1 = 8 in flight), then rendezvous
      if (more) { asm volatile("s_waitcnt vmcnt(8)" ::: "memory"); }
      else      { asm volatile("s_waitcnt vmcnt(4)" ::: "memory"); }
      __builtin_amdgcn_s_barrier();
      __builtin_amdgcn_sched_barrier(0);
      if (j0 <= wrow + 15) {   // wave-uniform causal skip (compute only)
        // ---- QK^T: S[16 i][32 j] as 2 frags ----
        f32x4 sfr[2] = {};
        __builtin_amdgcn_s_setprio(1);
#pragma unroll
        for (int ks = 0; ks < 16; ++ks) {
          short8 q0 = *(const short8*)(&sQ[cur][(size_t)(ks * 128 + lane) * 8]);
          short8 q1 = *(const short8*)(&sQ[cur][(size_t)(ks * 128 + 64 + lane) * 8]);
          sfr[0] = __builtin_amdgcn_mfma_f32_16x16x32_bf16(kf[ks], q0, sfr[0], 0, 0, 0);
          sfr[1] = __builtin_amdgcn_mfma_f32_16x16x32_bf16(kf[ks], q1, sfr[1], 0, 0, 0);
        }
        __builtin_amdgcn_s_setprio(0);
        if (j0 + 31 > wrow) {  // causal mask on diagonal tiles
#pragma unroll
          for (int jb = 0; jb < 2; ++jb)
#pragma unroll
            for (int r = 0; r < 4; ++r) {
              const int i = wrow + lg * 4 + r, j = j0 + jb * 16 + ln;
              if (j > i) sfr[jb][r] = -__builtin_inff();
            }
        }
        // ---- online softmax with defer-max (T13, THR=8) ----
        float mx[4];
#pragma unroll
        for (int r = 0; r < 4; ++r) mx[r] = fmaxf(sfr[0][r], sfr[1][r]);
#pragma unroll
        for (int d = 1; d < 16; d <<= 1)
#pragma unroll
          for (int r = 0; r < 4; ++r) mx[r] = fmaxf(mx[r], __shfl_xor(mx[r], d));
        bool need = false;
#pragma unroll
        for (int r = 0; r < 4; ++r) need |= !(mx[r] - m_r[r] <= 8.0f);  // NaN/inf-safe
        if (__any(need)) {
          float sc[4];
#pragma unroll
          for (int r = 0; r < 4; ++r) {
            float mm = fmaxf(fmaxf(m_r[r], mx[r]), -1e30f);  // clamp: no NaN
            sc[r] = __expf(m_r[r] - mm);
            m_r[r] = mm;
            l_r[r] *= sc[r];
          }
#pragma unroll
          for (int nb = 0; nb < 32; ++nb)
#pragma unroll
            for (int r = 0; r < 4; ++r) oa[nb][r] *= sc[r];
        }
        float ts[4] = {0.f, 0.f, 0.f, 0.f};
#pragma unroll
        for (int jb = 0; jb < 2; ++jb)
#pragma unroll
          for (int r = 0; r < 4; ++r) {
            float p = __expf(sfr[jb][r] - m_r[r]);
            sfr[jb][r] = p;
            ts[r] += p;
          }
#pragma unroll
        for (int d = 1; d < 16; d <<= 1)
#pragma unroll
          for (int r = 0; r < 4; ++r) ts[r] += __shfl_xor(ts[r], d);
#pragma unroll
        for (int r = 0; r < 4; ++r) l_r[r] += ts[r];
        // ---- P -> bf16 A-frag via per-wave LDS bounce ----
#pragma unroll
        for (int jb = 0; jb < 2; ++jb)
#pragma unroll
          for (int r = 0; r < 4; ++r)
            sP[wave][(lg * 4 + r) * 40 + jb * 16 + ln] = __float2bfloat16(sfr[jb][r]);
      }
      if (more) stageV(cur ^ 1, jt + 1);   // FIFO: [Vk Qk+1 Vk+1]
      // wait V(jt) landed (keep Qk+1 + Vk+1 = 8 in flight), then rendezvous
      if (more) { asm volatile("s_waitcnt vmcnt(8)" ::: "memory"); }
      else      { asm volatile("s_waitcnt vmcnt(0)" ::: "memory"); }
      __builtin_amdgcn_s_barrier();
      __builtin_amdgcn_sched_barrier(0);
      if (j0 <= wrow + 15) {
        const short8 pa = *(const short8*)(&sP[wave][0] + ln * 40 + lg * 8);
        // ---- PV: O[16][512] += P[16][32] * V[32][512], depth-4 rotation ----
        __builtin_amdgcn_s_setprio(1);
#define LDV(nb) (*(const short8*)(&sV[cur][(size_t)((nb) * 64 + lane) * 8]))
        short8 vf0 = LDV(0), vf1 = LDV(1), vf2 = LDV(2), vf3 = LDV(3);
#pragma unroll
        for (int nb = 0; nb < 28; nb += 4) {
          const short8 w0 = vf0, w1 = vf1, w2 = vf2, w3 = vf3;
          vf0 = LDV(nb + 4); vf1 = LDV(nb + 5); vf2 = LDV(nb + 6); vf3 = LDV(nb + 7);
          oa[nb]     = __builtin_amdgcn_mfma_f32_16x16x32_bf16(pa, w0, oa[nb],     0, 0, 0);
          oa[nb + 1] = __builtin_amdgcn_mfma_f32_16x16x32_bf16(pa, w1, oa[nb + 1], 0, 0, 0);
          oa[nb + 2] = __builtin_amdgcn_mfma_f32_16x16x32_bf16(pa, w2, oa[nb + 2], 0, 0, 0);
          oa[nb + 3] = __builtin_amdgcn_mfma_f32_16x16x32_bf16(pa, w3, oa[nb + 3], 0, 0, 0);
        }
        oa[28] = __builtin_amdgcn_mfma_f32_16x16x32_bf16(pa, vf0, oa[28], 0, 0, 0);
        oa[29] = __builtin_amdgcn_mfma_f32_16x16x32_bf16(pa, vf1, oa[29], 0, 0, 0);
        oa[30] = __builtin_amdgcn_mfma_f32_16x16x32_bf16(pa, vf2, oa[30], 0, 0, 0);
        oa[31] = __builtin_amdgcn_mfma_f32_16x16x32_bf16(pa, vf3, oa[31], 0, 0, 0);
#undef LDV
        __builtin_amdgcn_s_setprio(0);
      }
      cur ^= 1;
    }
  }
  // ---- write partials (bf16, per-element; verified epilogue) ----
#pragma unroll
  for (int nb = 0; nb < 32; ++nb)
#pragma unroll
    for (int r = 0; r < 4; ++r)
      Op[((size_t)ch * T_DIM + wrow + lg * 4 + r) * 512 + nb * 16 + ln] = __float2bfloat16(oa[nb][r]);
  if (ln == 0) {
#pragma unroll
    for (int r = 0; r < 4; ++r) {
      mlp[((size_t)ch * T_DIM + wrow + lg * 4 + r) * 2 + 0] = m_r[r];
      mlp[((size_t)ch * T_DIM + wrow + lg * 4 + r) * 2 + 1] = l_r[r];
    }
  }
}

// ---------------- merge attention partials -> o bf16 [T,512] ----------------
__global__ __launch_bounds__(256) void combine_kernel(
    const bf16* __restrict__ Op, const float* __restrict__ mlp, bf16* __restrict__ o)
{
  const int row = blockIdx.x * 4 + (threadIdx.x >> 6);
  const int lane = threadIdx.x & 63;
  const int k = 8;  // uniform 8 chunks per row-tile
  float m = -__builtin_inff();
  for (int c = 0; c < k; ++c) m = fmaxf(m, mlp[((size_t)c * T_DIM + row) * 2]);
  float l = 0.f;
  for (int c = 0; c < k; ++c) {
    const float mc = mlp[((size_t)c * T_DIM + row) * 2];
    const float lc = mlp[((size_t)c * T_DIM + row) * 2 + 1];
    l += __expf(mc - m) * lc;
  }
  const float inv = 1.0f / l;
  f32x4 a0 = {}, a1 = {};
  for (int c = 0; c < k; ++c) {
    const float w = __expf(mlp[((size_t)c * T_DIM + row) * 2] - m);
    const short8 u = *(const short8*)(Op + ((size_t)c * T_DIM + row) * 512 + lane * 8);
#pragma unroll
    for (int j = 0; j < 4; ++j) {
      a0[j] += w * bfbits2f(u[j]);
      a1[j] += w * bfbits2f(u[j + 4]);
    }
  }
  short8 ov;
#pragma unroll
  for (int j = 0; j < 4; ++j) {
    ov[j]     = f2bfbits(a0[j] * inv);
    ov[j + 4] = f2bfbits(a1[j] * inv);
  }
  *(short8*)(o + (size_t)row * 512 + lane * 8) = ov;
}

// ---------------- launch ----------------
extern "C" void kernel_launch(void* const* d_in, const int* in_sizes, int n_in,
                              void* d_out, int out_size, void* d_ws, size_t ws_size,
                              hipStream_t stream) {
  (void)in_sizes; (void)n_in; (void)out_size; (void)ws_size;
  const float* x    = (const float*)d_in[0];
  const float* Win  = (const float*)d_in[1];
  const float* Wout = (const float*)d_in[2];
  const float* W1   = (const float*)d_in[3];
  const float* W2   = (const float*)d_in[4];
  const float* g1   = (const float*)d_in[5];
  const float* b1   = (const float*)d_in[6];
  const float* g2   = (const float*)d_in[7];
  const float* b2   = (const float*)d_in[8];
  const float* ls1  = (const float*)d_in[9];
  const float* ls2  = (const float*)d_in[10];
  float* out = (float*)d_out;

  char* w = (char*)d_ws;
  size_t off = 0;
  auto alloc = [&](size_t bytes) -> char* {
    char* p = w + off; off += (bytes + 255) & ~(size_t)255; return p;
  };
  bf16* wWin  = (bf16*)alloc((size_t)1536 * 512 * 2);
  bf16* wWout = (bf16*)alloc((size_t)512 * 512 * 2);
  bf16* wW1   = (bf16*)alloc((size_t)2048 * 512 * 2);
  bf16* wW2   = (bf16*)alloc((size_t)512 * 2048 * 2);
  bf16* h     = (bf16*)alloc((size_t)T_DIM * 512 * 2);    // LN1 out; reused for LN2 out
  bf16* proj  = (bf16*)alloc((size_t)T_DIM * 1536 * 2);   // q|k|v
  bf16* vTb   = (bf16*)alloc((size_t)512 * T_DIM * 2);
  bf16* o     = (bf16*)alloc((size_t)T_DIM * 512 * 2);
  float* x1   = (float*)alloc((size_t)T_DIM * 512 * 4);
  bf16* Op    = (bf16*)alloc((size_t)8 * T_DIM * 512 * 2); // 67MB bf16 partials
  float* mlp  = (float*)alloc((size_t)8 * T_DIM * 2 * 4);
  bf16* f1 = proj;  // ffn1 out aliases proj||vT (dead after attention)

  cvt4_kernel<<<(1536 * 512 + 512 * 512 + 2048 * 512 + 512 * 2048) / 4 / 256, 256, 0, stream>>>(
      Win, wWin, 1536 * 512, Wout, wWout, 512 * 512,
      W1, wW1, 2048 * 512, W2, wW2, 512 * 2048);

  ln_kernel<<<T_DIM / 4, 256, 0, stream>>>(x, g1, b1, h);
  gemm_bt<MODE_BF16><<<dim3(64, 12), 256, 0, stream>>>(h, wWin, 8192, 1536, 512, proj, nullptr, nullptr, nullptr);
  transpose_v<<<dim3(T_DIM / 64, 8), 256, 0, stream>>>(proj, vTb);
  attn_kernel<<<512, 512, 0, stream>>>(proj, vTb, Op, mlp);
  combine_kernel<<<T_DIM / 4, 256, 0, stream>>>(Op, mlp, o);
  gemm_bt<MODE_RESID><<<dim3(64, 4), 256, 0, stream>>>(o, wWout, 8192, 512, 512, nullptr, x1, x, ls1);
  ln_kernel<<<T_DIM / 4, 256, 0, stream>>>(x1, g2, b2, h);
  gemm_bt<MODE_GELU><<<dim3(64, 16), 256, 0, stream>>>(h, wW1, 8192, 2048, 512, f1, nullptr, nullptr, nullptr);
  gemm_bt<MODE_RESID><<<dim3(64, 4), 256, 0, stream>>>(f1, wW2, 8192, 512, 2048, nullptr, out, x1, ls2);
}